// Round 4
// baseline (462.793 us; speedup 1.0000x reference)
//
#include <hip/hip_runtime.h>
#include <hip/hip_bf16.h>

typedef __attribute__((ext_vector_type(8))) short bf16x8;
typedef __attribute__((ext_vector_type(4))) float f32x4;

#define B_    4
#define L_    2048
#define D_    256
#define H_    8
#define DH_   32
#define DFF_  1024
#define BL_   (B_*L_)          // 8192
#define RES_ELEMS (BL_*D_)     // 2097152
#define STP   2088             // padded LDS row stride (bf16 elems)

__device__ __forceinline__ float bf2f(ushort u){
  union { unsigned int i; float f; } v; v.i = ((unsigned int)u)<<16; return v.f;
}
__device__ __forceinline__ ushort f2bf(float f){
  union { float f; unsigned int i; } v; v.f = f;
  unsigned int u = v.i;
  u += 0x7fffu + ((u>>16)&1u);   // round-to-nearest-even
  return (ushort)(u>>16);
}

// ---------------- prep: fp32 -> bf16 casts + weight transposes ----------------
__global__ void prep_kernel(const float* x, const float* Wq, const float* Wk, const float* Wv,
                            const float* Wo, const float* W1, const float* W2,
                            ushort* xb, ushort* wqt, ushort* wkt, ushort* wvt, ushort* wot,
                            ushort* w1b, ushort* w2b){
  int i = blockIdx.x*256 + threadIdx.x;
  const int NX = BL_*D_;
  const int NW = D_*D_;
  const int NF = DFF_*D_;
  if (i < NX) { xb[i] = f2bf(x[i]); return; }
  i -= NX;
  if (i < NW) { int c = i>>8, k = i&255; wqt[i] = f2bf(Wq[k*D_+c]); return; }
  i -= NW;
  if (i < NW) { int c = i>>8, k = i&255; wkt[i] = f2bf(Wk[k*D_+c]); return; }
  i -= NW;
  if (i < NW) { int c = i>>8, k = i&255; wvt[i] = f2bf(Wv[k*D_+c]); return; }
  i -= NW;
  if (i < NW) { int c = i>>8, k = i&255; wot[i] = f2bf(Wo[k*D_+c]); return; }
  i -= NW;
  if (i < NF) { w1b[i] = f2bf(W1[i]); return; }
  i -= NF;
  if (i < NF) { w2b[i] = f2bf(W2[i]); return; }
}

// ---------------- QKV projection GEMM (q,k row-major; v head-transposed) ----------------
__global__ __launch_bounds__(256) void qkv_gemm(const ushort* __restrict__ xb,
                         const ushort* __restrict__ wqt, const ushort* __restrict__ wkt,
                         const ushort* __restrict__ wvt,
                         ushort* __restrict__ qb, ushort* __restrict__ kb, ushort* __restrict__ vtb){
  int lane = threadIdx.x & 63, w = threadIdx.x >> 6;
  int rt = blockIdx.x, cg = blockIdx.y, mat = blockIdx.z;
  const ushort* Bt = (mat==0) ? wqt : (mat==1) ? wkt : wvt;
  int row = rt*16 + (lane & 15);
  int col = cg*64 + w*16 + (lane & 15);
  int kseg = lane >> 4;
  f32x4 acc = {0.f,0.f,0.f,0.f};
  #pragma unroll
  for (int kt = 0; kt < 8; ++kt){
    bf16x8 a = *(const bf16x8*)(xb + row*D_ + kt*32 + kseg*8);
    bf16x8 b = *(const bf16x8*)(Bt + col*D_ + kt*32 + kseg*8);
    acc = __builtin_amdgcn_mfma_f32_16x16x32_bf16(a, b, acc, 0, 0, 0);
  }
  int rbase = rt*16 + (lane>>4)*4;   // C/D: row=(lane>>4)*4+r, col=lane&15
  if (mat < 2){
    ushort* out = (mat==0) ? qb : kb;
    #pragma unroll
    for (int r = 0; r < 4; ++r) out[(size_t)(rbase+r)*D_ + col] = f2bf(acc[r]);
  } else {
    int b = rbase >> 11, l = rbase & (L_-1);
    int h = col >> 5, d = col & 31;
    ushort* p = vtb + ((size_t)((b*H_ + h)*DH_ + d))*L_ + l;
    #pragma unroll
    for (int r = 0; r < 4; ++r) p[r] = f2bf(acc[r]);
  }
}

// ---------------- attention: S tile in LDS, softmax, fp32 attn write, PV ----------------
__global__ __launch_bounds__(256) void attn_kernel(const ushort* __restrict__ qb,
                          const ushort* __restrict__ kb, const ushort* __restrict__ vtb,
                          float* __restrict__ attn_out, ushort* __restrict__ ob){
  __shared__ ushort S[16*STP];
  __shared__ float part[4*16*32];
  int tid = threadIdx.x, lane = tid & 63, w = tid >> 6;
  int rt = blockIdx.x, bh = blockIdx.y;
  int b = bh >> 3, h = bh & 7;
  int l0 = rt*16;
  const float SCL2E = 0.17677669529663687f * 1.4426950408889634f; // 1/sqrt(32) * log2(e)
  int kseg = lane >> 4;

  int arow = l0 + (lane & 15);
  bf16x8 qfrag = *(const bf16x8*)(qb + (size_t)(b*L_ + arow)*D_ + h*DH_ + kseg*8);

  // Phase 1: S = Q K^T (raw) into LDS as bf16
  for (int ct = w; ct < 128; ct += 4){
    int colB = ct*16 + (lane & 15);
    bf16x8 kfrag = *(const bf16x8*)(kb + (size_t)(b*L_ + colB)*D_ + h*DH_ + kseg*8);
    f32x4 acc = {0.f,0.f,0.f,0.f};
    acc = __builtin_amdgcn_mfma_f32_16x16x32_bf16(qfrag, kfrag, acc, 0, 0, 0);
    int rb = (lane>>4)*4, cc = ct*16 + (lane & 15);
    #pragma unroll
    for (int r = 0; r < 4; ++r) S[(rb+r)*STP + cc] = f2bf(acc[r]);
  }
  __syncthreads();

  // Phase 2: row softmax; write fp32 attn + bf16 P back to LDS
  for (int rr = 0; rr < 4; ++rr){
    int row = w*4 + rr;
    float vals[32];
    float m = -1e30f;
    #pragma unroll
    for (int i = 0; i < 32; ++i){
      float v = bf2f(S[row*STP + lane + 64*i]);
      vals[i] = v; m = fmaxf(m, v);
    }
    #pragma unroll
    for (int off = 32; off >= 1; off >>= 1) m = fmaxf(m, __shfl_xor(m, off));
    float sum = 0.f;
    #pragma unroll
    for (int i = 0; i < 32; ++i){
      float p = exp2f((vals[i] - m) * SCL2E);
      vals[i] = p; sum += p;
    }
    #pragma unroll
    for (int off = 32; off >= 1; off >>= 1) sum += __shfl_xor(sum, off);
    float rinv = 1.f / sum;
    float* gout = attn_out + ((size_t)bh*L_ + l0 + row)*L_ + lane;
    #pragma unroll
    for (int i = 0; i < 32; ++i){
      float p = vals[i]*rinv;
      S[row*STP + lane + 64*i] = f2bf(p);   // P for PV
      gout[64*i] = p;                        // fp32 attn output (coalesced)
    }
  }
  __syncthreads();

  // Phase 3: P x V
  f32x4 acc0 = {0.f,0.f,0.f,0.f}, acc1 = {0.f,0.f,0.f,0.f};
  int prow = lane & 15;
  const ushort* v0p = vtb + ((size_t)(bh*DH_) + (lane&15))*L_;
  const ushort* v1p = vtb + ((size_t)(bh*DH_) + 16 + (lane&15))*L_;
  for (int kt = w*16; kt < w*16 + 16; ++kt){
    bf16x8 pf = *(const bf16x8*)(&S[prow*STP + kt*32 + kseg*8]);
    bf16x8 v0 = *(const bf16x8*)(v0p + kt*32 + kseg*8);
    bf16x8 v1 = *(const bf16x8*)(v1p + kt*32 + kseg*8);
    acc0 = __builtin_amdgcn_mfma_f32_16x16x32_bf16(pf, v0, acc0, 0, 0, 0);
    acc1 = __builtin_amdgcn_mfma_f32_16x16x32_bf16(pf, v1, acc1, 0, 0, 0);
  }
  {
    int rb = (lane>>4)*4;
    #pragma unroll
    for (int r = 0; r < 4; ++r){
      part[(w*16 + rb + r)*32 + (lane&15)]      = acc0[r];
      part[(w*16 + rb + r)*32 + 16 + (lane&15)] = acc1[r];
    }
  }
  __syncthreads();
  for (int idx = tid; idx < 512; idx += 256){
    int row = idx >> 5, d = idx & 31;
    float s = part[(0*16+row)*32 + d] + part[(1*16+row)*32 + d]
            + part[(2*16+row)*32 + d] + part[(3*16+row)*32 + d];
    ob[(size_t)(b*L_ + l0 + row)*D_ + h*DH_ + d] = f2bf(s);
  }
}

// ---------------- generic GEMM C = A[MxK] * Bt[NxK]^T with epilogue ----------------
// EPI 1: out_bf16 = relu(acc);  EPI 2: out_f32 = add[o] + acc
template<int EPI>
__global__ __launch_bounds__(256) void gemm_bt(const ushort* __restrict__ A, const ushort* __restrict__ Bt,
                        int M, int N, int K,
                        const float* __restrict__ add, float* __restrict__ outf,
                        ushort* __restrict__ outh){
  int lane = threadIdx.x & 63, w = threadIdx.x >> 6;
  int row = blockIdx.x*16 + (lane & 15);
  int col = blockIdx.y*64 + w*16 + (lane & 15);
  int kseg = lane >> 4;
  f32x4 acc = {0.f,0.f,0.f,0.f};
  const ushort* ap = A + (size_t)row*K + kseg*8;
  const ushort* bp = Bt + (size_t)col*K + kseg*8;
  int nk = K >> 5;
  for (int kt = 0; kt < nk; ++kt){
    bf16x8 a = *(const bf16x8*)(ap + kt*32);
    bf16x8 bfr = *(const bf16x8*)(bp + kt*32);
    acc = __builtin_amdgcn_mfma_f32_16x16x32_bf16(a, bfr, acc, 0, 0, 0);
  }
  int rbase = blockIdx.x*16 + (lane>>4)*4;
  #pragma unroll
  for (int r = 0; r < 4; ++r){
    size_t o = (size_t)(rbase + r)*N + col;
    float v = acc[r];
    if (EPI == 1) outh[o] = f2bf(fmaxf(v, 0.f));
    else if (EPI == 2) outf[o] = add[o] + v;
  }
}

// ---------------- circular moving-average decomp ----------------
// WHICH 0: write fp32 + bf16 (FFN input); WHICH 1: write fp32 res (harness output)
template<int WHICH>
__global__ __launch_bounds__(256) void decomp_kernel(const float* __restrict__ in,
                                                     float* __restrict__ outf,
                                                     ushort* __restrict__ outh){
  int c = threadIdx.x;
  int gl = blockIdx.x;
  int b = gl >> 11, l = gl & (L_-1);
  float s = 0.f;
  #pragma unroll
  for (int o = -3; o <= 3; ++o){
    int ll = (l + o + L_) & (L_-1);
    s += in[((size_t)(b*L_ + ll))*D_ + c];
  }
  float v = in[(size_t)gl*D_ + c] - s*(1.f/7.f);
  if (WHICH == 0){
    outf[(size_t)gl*D_ + c] = v;
    outh[(size_t)gl*D_ + c] = f2bf(v);
  } else {
    outf[(size_t)gl*D_ + c] = v;   // fp32 final res
  }
}

// ---------------- diagnostic sentinel (fp32 now) ----------------
__global__ void ws_diag_kernel(float* res0, float encoded){
  if (threadIdx.x == 0 && blockIdx.x == 0) res0[0] = encoded;
}

extern "C" void kernel_launch(void* const* d_in, const int* in_sizes, int n_in,
                              void* d_out, int out_size, void* d_ws, size_t ws_size,
                              hipStream_t stream) {
  const float* x  = (const float*)d_in[0];
  const float* Wq = (const float*)d_in[1];
  const float* Wk = (const float*)d_in[2];
  const float* Wv = (const float*)d_in[3];
  const float* Wo = (const float*)d_in[4];
  const float* W1 = (const float*)d_in[5];
  const float* W2 = (const float*)d_in[6];

  float* out      = (float*)d_out;        // fp32 outputs (reference dtype)
  float* res_out  = out;                  // res: 2,097,152 fp32
  float* attn_out = out + RES_ELEMS;      // attn: 134,217,728 fp32

  const size_t MiB = 1024ull*1024ull;
  const size_t NEEDED = 36*MiB + (MiB + MiB/2);   // 37.5 MiB (proven to fit: r2/r3 sentinel never fired)

  if (ws_size < NEEDED){
    float enc = 1048576.0f + 1024.0f * (float)(ws_size / MiB);
    ws_diag_kernel<<<1, 64, 0, stream>>>(res_out, enc);
    return;
  }

  char* ws = (char*)d_ws;
  // lifetime-aliased layout (37.5 MiB):
  //  [0,4)    : xb  -> ob  -> xdb
  //  [4,12)   : qb(4)+kb(4) -> x1f(fp32,8) -> sf(fp32,8)
  //  [12,20)  : vtb(4)+free -> xdf(fp32,8)
  //  [20,36)  : hb(16)
  //  [36,37.5): bf16 weights
  ushort* xb  = (ushort*)(ws + 0);
  ushort* ob  = (ushort*)(ws + 0);
  ushort* xdb = (ushort*)(ws + 0);
  ushort* qb  = (ushort*)(ws + 4*MiB);
  ushort* kb  = (ushort*)(ws + 8*MiB);
  float*  x1f = (float*) (ws + 4*MiB);
  float*  sf  = (float*) (ws + 4*MiB);
  ushort* vtb = (ushort*)(ws + 12*MiB);
  float*  xdf = (float*) (ws + 12*MiB);
  ushort* hb  = (ushort*)(ws + 20*MiB);
  ushort* wqt = (ushort*)(ws + 36*MiB);
  ushort* wkt = (ushort*)(ws + 36*MiB + 128*1024);
  ushort* wvt = (ushort*)(ws + 36*MiB + 256*1024);
  ushort* wot = (ushort*)(ws + 36*MiB + 384*1024);
  ushort* w1b = (ushort*)(ws + 36*MiB + 512*1024);
  ushort* w2b = (ushort*)(ws + 36*MiB + 1024*1024);

  // 1. prep
  {
    int total = BL_*D_ + 4*D_*D_ + 2*DFF_*D_;
    prep_kernel<<<(total+255)/256, 256, 0, stream>>>(x, Wq, Wk, Wv, Wo, W1, W2,
                                                     xb, wqt, wkt, wvt, wot, w1b, w2b);
  }
  // 2. QKV projections
  qkv_gemm<<<dim3(BL_/16, 4, 3), 256, 0, stream>>>(xb, wqt, wkt, wvt, qb, kb, vtb);
  // 3. attention (fp32 attn output + bf16 ob)
  attn_kernel<<<dim3(L_/16, B_*H_), 256, 0, stream>>>(qb, kb, vtb, attn_out, ob);
  // 4. O projection + residual: x1f = x + ob @ Wo
  gemm_bt<2><<<dim3(BL_/16, D_/64), 256, 0, stream>>>(ob, wot, BL_, D_, D_, x, x1f, nullptr);
  // 5. decomp1
  decomp_kernel<0><<<BL_, 256, 0, stream>>>(x1f, xdf, xdb);
  // 6. FFN1
  gemm_bt<1><<<dim3(BL_/16, DFF_/64), 256, 0, stream>>>(xdb, w1b, BL_, DFF_, D_, nullptr, nullptr, hb);
  // 7. FFN2 + residual
  gemm_bt<2><<<dim3(BL_/16, D_/64), 256, 0, stream>>>(hb, w2b, BL_, D_, DFF_, xdf, sf, nullptr);
  // 8. decomp2 -> fp32 res
  decomp_kernel<1><<<BL_, 256, 0, stream>>>(sf, res_out, nullptr);
}

// Round 5
// 457.666 us; speedup vs baseline: 1.0112x; 1.0112x over previous
//
#include <hip/hip_runtime.h>
#include <hip/hip_bf16.h>

typedef __attribute__((ext_vector_type(8))) short bf16x8;
typedef __attribute__((ext_vector_type(4))) float f32x4;

#define B_    4
#define L_    2048
#define D_    256
#define H_    8
#define DH_   32
#define DFF_  1024
#define BL_   (B_*L_)          // 8192
#define RES_ELEMS (BL_*D_)     // 2097152
#define STP   2088             // padded LDS row stride (bf16 elems)

__device__ __forceinline__ float bf2f(ushort u){
  union { unsigned int i; float f; } v; v.i = ((unsigned int)u)<<16; return v.f;
}
__device__ __forceinline__ ushort f2bf(float f){
  union { float f; unsigned int i; } v; v.f = f;
  unsigned int u = v.i;
  u += 0x7fffu + ((u>>16)&1u);   // round-to-nearest-even
  return (ushort)(u>>16);
}

// ---------------- prep: fp32 -> bf16 casts + weight transposes (UNCHANGED r4) ----------------
__global__ void prep_kernel(const float* x, const float* Wq, const float* Wk, const float* Wv,
                            const float* Wo, const float* W1, const float* W2,
                            ushort* xb, ushort* wqt, ushort* wkt, ushort* wvt, ushort* wot,
                            ushort* w1b, ushort* w2b){
  int i = blockIdx.x*256 + threadIdx.x;
  const int NX = BL_*D_;
  const int NW = D_*D_;
  const int NF = DFF_*D_;
  if (i < NX) { xb[i] = f2bf(x[i]); return; }
  i -= NX;
  if (i < NW) { int c = i>>8, k = i&255; wqt[i] = f2bf(Wq[k*D_+c]); return; }
  i -= NW;
  if (i < NW) { int c = i>>8, k = i&255; wkt[i] = f2bf(Wk[k*D_+c]); return; }
  i -= NW;
  if (i < NW) { int c = i>>8, k = i&255; wvt[i] = f2bf(Wv[k*D_+c]); return; }
  i -= NW;
  if (i < NW) { int c = i>>8, k = i&255; wot[i] = f2bf(Wo[k*D_+c]); return; }
  i -= NW;
  if (i < NF) { w1b[i] = f2bf(W1[i]); return; }
  i -= NF;
  if (i < NF) { w2b[i] = f2bf(W2[i]); return; }
}

// ---------------- QKV projection GEMM (UNCHANGED r4) ----------------
__global__ __launch_bounds__(256) void qkv_gemm(const ushort* __restrict__ xb,
                         const ushort* __restrict__ wqt, const ushort* __restrict__ wkt,
                         const ushort* __restrict__ wvt,
                         ushort* __restrict__ qb, ushort* __restrict__ kb, ushort* __restrict__ vtb){
  int lane = threadIdx.x & 63, w = threadIdx.x >> 6;
  int rt = blockIdx.x, cg = blockIdx.y, mat = blockIdx.z;
  const ushort* Bt = (mat==0) ? wqt : (mat==1) ? wkt : wvt;
  int row = rt*16 + (lane & 15);
  int col = cg*64 + w*16 + (lane & 15);
  int kseg = lane >> 4;
  f32x4 acc = {0.f,0.f,0.f,0.f};
  #pragma unroll
  for (int kt = 0; kt < 8; ++kt){
    bf16x8 a = *(const bf16x8*)(xb + row*D_ + kt*32 + kseg*8);
    bf16x8 b = *(const bf16x8*)(Bt + col*D_ + kt*32 + kseg*8);
    acc = __builtin_amdgcn_mfma_f32_16x16x32_bf16(a, b, acc, 0, 0, 0);
  }
  int rbase = rt*16 + (lane>>4)*4;   // C/D: row=(lane>>4)*4+r, col=lane&15
  if (mat < 2){
    ushort* out = (mat==0) ? qb : kb;
    #pragma unroll
    for (int r = 0; r < 4; ++r) out[(size_t)(rbase+r)*D_ + col] = f2bf(acc[r]);
  } else {
    int b = rbase >> 11, l = rbase & (L_-1);
    int h = col >> 5, d = col & 31;
    ushort* p = vtb + ((size_t)((b*H_ + h)*DH_ + d))*L_ + l;
    #pragma unroll
    for (int r = 0; r < 4; ++r) p[r] = f2bf(acc[r]);
  }
}

// ---------------- attention v2: swapped QK^T, in-register online softmax ----------------
// grid (L_/16, B_*H_), block 256 (4 waves). Wave w owns k-tiles ct in [w*32, w*32+32).
// D = mfma(A=K_tile, B=Q_tile): lane holds S^T: q = lane&15, k = ct*16 + (lane>>4)*4 + r
// -> 4 consecutive k per lane -> float4 attn store + b64 bf16 P store.
__global__ __launch_bounds__(256) void attn_kernel(const ushort* __restrict__ qb,
                          const ushort* __restrict__ kb, const ushort* __restrict__ vtb,
                          float* __restrict__ attn_out, ushort* __restrict__ ob){
  __shared__ ushort P[16*STP];          // normalized P (bf16) for PV
  __shared__ float part[4*16*32];       // per-wave PV partials
  __shared__ float red[4][2][16];       // per-wave (m,s) per q-row
  int tid = threadIdx.x, lane = tid & 63, w = tid >> 6;
  int rt = blockIdx.x, bh = blockIdx.y;
  int b = bh >> 3, h = bh & 7;
  int l0 = rt*16;
  int ql = lane & 15, g = lane >> 4;    // q-row within tile, k-subgroup
  const float SCL2E = 0.17677669529663687f * 1.4426950408889634f; // 1/sqrt(32) * log2(e)

  // Q fragment (B-operand), reused across both passes
  bf16x8 qfrag = *(const bf16x8*)(qb + (size_t)(b*L_ + l0 + ql)*D_ + h*DH_ + g*8);
  const ushort* kbase = kb + (size_t)(b)*L_*D_ + h*DH_ + g*8;

  // ---- pass A: online max/sum over this wave's k-range ----
  float m = -1e30f, s = 0.f;
  for (int ct = w*32; ct < w*32 + 32; ++ct){
    bf16x8 kfrag = *(const bf16x8*)(kbase + (size_t)(ct*16 + ql)*D_);
    f32x4 acc = {0.f,0.f,0.f,0.f};
    acc = __builtin_amdgcn_mfma_f32_16x16x32_bf16(kfrag, qfrag, acc, 0, 0, 0);
    float z0 = acc[0]*SCL2E, z1 = acc[1]*SCL2E, z2 = acc[2]*SCL2E, z3 = acc[3]*SCL2E;
    float mt = fmaxf(fmaxf(z0, z1), fmaxf(z2, z3));
    float mn = fmaxf(m, mt);
    s = s*exp2f(m - mn) + (exp2f(z0 - mn) + exp2f(z1 - mn))
                        + (exp2f(z2 - mn) + exp2f(z3 - mn));
    m = mn;
  }
  // merge the 4 k-subgroups sharing a q-row (lanes ql, ql+16, ql+32, ql+48)
  #pragma unroll
  for (int off = 16; off <= 32; off <<= 1){
    float mo = __shfl_xor(m, off), so = __shfl_xor(s, off);
    float mn = fmaxf(m, mo);
    s = s*exp2f(m - mn) + so*exp2f(mo - mn);
    m = mn;
  }
  if (lane < 16){ red[w][0][ql] = m; red[w][1][ql] = s; }
  __syncthreads();
  {
    float M = red[0][0][ql], S = red[0][1][ql];
    #pragma unroll
    for (int w2 = 1; w2 < 4; ++w2){
      float mo = red[w2][0][ql], so = red[w2][1][ql];
      float mn = fmaxf(M, mo);
      S = S*exp2f(M - mn) + so*exp2f(mo - mn);
      M = mn;
    }
    m = M; s = S;
  }
  float rinv = 1.f / s;

  // ---- pass B: recompute scores, write normalized fp32 attn + bf16 P ----
  float* arow = attn_out + ((size_t)bh*L_ + l0 + ql)*L_;
  for (int ct = w*32; ct < w*32 + 32; ++ct){
    bf16x8 kfrag = *(const bf16x8*)(kbase + (size_t)(ct*16 + ql)*D_);
    f32x4 acc = {0.f,0.f,0.f,0.f};
    acc = __builtin_amdgcn_mfma_f32_16x16x32_bf16(kfrag, qfrag, acc, 0, 0, 0);
    float p0 = exp2f(acc[0]*SCL2E - m)*rinv;
    float p1 = exp2f(acc[1]*SCL2E - m)*rinv;
    float p2 = exp2f(acc[2]*SCL2E - m)*rinv;
    float p3 = exp2f(acc[3]*SCL2E - m)*rinv;
    float4 st = {p0, p1, p2, p3};
    *(float4*)(arow + ct*16 + g*4) = st;                       // 16B coalesced attn write
    ushort4 u4 = {f2bf(p0), f2bf(p1), f2bf(p2), f2bf(p3)};
    *(ushort4*)(&P[ql*STP + ct*16 + g*4]) = u4;                // bf16 P for PV (8B LDS write)
  }

  // ---- PV: wave w covers its own k-range [w*512, w*512+512) -> no barrier needed ----
  f32x4 acc0 = {0.f,0.f,0.f,0.f}, acc1 = {0.f,0.f,0.f,0.f};
  int kseg = g;
  const ushort* v0p = vtb + ((size_t)(bh*DH_) + ql)*L_;
  const ushort* v1p = vtb + ((size_t)(bh*DH_) + 16 + ql)*L_;
  for (int kt = w*16; kt < w*16 + 16; ++kt){
    bf16x8 pf = *(const bf16x8*)(&P[ql*STP + kt*32 + kseg*8]);
    bf16x8 v0 = *(const bf16x8*)(v0p + kt*32 + kseg*8);
    bf16x8 v1 = *(const bf16x8*)(v1p + kt*32 + kseg*8);
    acc0 = __builtin_amdgcn_mfma_f32_16x16x32_bf16(pf, v0, acc0, 0, 0, 0);
    acc1 = __builtin_amdgcn_mfma_f32_16x16x32_bf16(pf, v1, acc1, 0, 0, 0);
  }
  {
    int rb = g*4;
    #pragma unroll
    for (int r = 0; r < 4; ++r){
      part[(w*16 + rb + r)*32 + ql]      = acc0[r];
      part[(w*16 + rb + r)*32 + 16 + ql] = acc1[r];
    }
  }
  __syncthreads();
  for (int idx = tid; idx < 512; idx += 256){
    int row = idx >> 5, d = idx & 31;
    float sum = part[(0*16+row)*32 + d] + part[(1*16+row)*32 + d]
              + part[(2*16+row)*32 + d] + part[(3*16+row)*32 + d];
    ob[(size_t)(b*L_ + l0 + row)*D_ + h*DH_ + d] = f2bf(sum);
  }
}

// ---------------- generic GEMM (UNCHANGED r4) ----------------
template<int EPI>
__global__ __launch_bounds__(256) void gemm_bt(const ushort* __restrict__ A, const ushort* __restrict__ Bt,
                        int M, int N, int K,
                        const float* __restrict__ add, float* __restrict__ outf,
                        ushort* __restrict__ outh){
  int lane = threadIdx.x & 63, w = threadIdx.x >> 6;
  int row = blockIdx.x*16 + (lane & 15);
  int col = blockIdx.y*64 + w*16 + (lane & 15);
  int kseg = lane >> 4;
  f32x4 acc = {0.f,0.f,0.f,0.f};
  const ushort* ap = A + (size_t)row*K + kseg*8;
  const ushort* bp = Bt + (size_t)col*K + kseg*8;
  int nk = K >> 5;
  for (int kt = 0; kt < nk; ++kt){
    bf16x8 a = *(const bf16x8*)(ap + kt*32);
    bf16x8 bfr = *(const bf16x8*)(bp + kt*32);
    acc = __builtin_amdgcn_mfma_f32_16x16x32_bf16(a, bfr, acc, 0, 0, 0);
  }
  int rbase = blockIdx.x*16 + (lane>>4)*4;
  #pragma unroll
  for (int r = 0; r < 4; ++r){
    size_t o = (size_t)(rbase + r)*N + col;
    float v = acc[r];
    if (EPI == 1) outh[o] = f2bf(fmaxf(v, 0.f));
    else if (EPI == 2) outf[o] = add[o] + v;
  }
}

// ---------------- circular moving-average decomp (UNCHANGED r4) ----------------
template<int WHICH>
__global__ __launch_bounds__(256) void decomp_kernel(const float* __restrict__ in,
                                                     float* __restrict__ outf,
                                                     ushort* __restrict__ outh){
  int c = threadIdx.x;
  int gl = blockIdx.x;
  int b = gl >> 11, l = gl & (L_-1);
  float s = 0.f;
  #pragma unroll
  for (int o = -3; o <= 3; ++o){
    int ll = (l + o + L_) & (L_-1);
    s += in[((size_t)(b*L_ + ll))*D_ + c];
  }
  float v = in[(size_t)gl*D_ + c] - s*(1.f/7.f);
  if (WHICH == 0){
    outf[(size_t)gl*D_ + c] = v;
    outh[(size_t)gl*D_ + c] = f2bf(v);
  } else {
    outf[(size_t)gl*D_ + c] = v;   // fp32 final res
  }
}

__global__ void ws_diag_kernel(float* res0, float encoded){
  if (threadIdx.x == 0 && blockIdx.x == 0) res0[0] = encoded;
}

extern "C" void kernel_launch(void* const* d_in, const int* in_sizes, int n_in,
                              void* d_out, int out_size, void* d_ws, size_t ws_size,
                              hipStream_t stream) {
  const float* x  = (const float*)d_in[0];
  const float* Wq = (const float*)d_in[1];
  const float* Wk = (const float*)d_in[2];
  const float* Wv = (const float*)d_in[3];
  const float* Wo = (const float*)d_in[4];
  const float* W1 = (const float*)d_in[5];
  const float* W2 = (const float*)d_in[6];

  float* out      = (float*)d_out;        // fp32 outputs
  float* res_out  = out;                  // res: 2,097,152 fp32
  float* attn_out = out + RES_ELEMS;      // attn: 134,217,728 fp32

  const size_t MiB = 1024ull*1024ull;
  const size_t NEEDED = 36*MiB + (MiB + MiB/2);   // 37.5 MiB (fits, r2-r4 verified)

  if (ws_size < NEEDED){
    float enc = 1048576.0f + 1024.0f * (float)(ws_size / MiB);
    ws_diag_kernel<<<1, 64, 0, stream>>>(res_out, enc);
    return;
  }

  char* ws = (char*)d_ws;
  ushort* xb  = (ushort*)(ws + 0);
  ushort* ob  = (ushort*)(ws + 0);
  ushort* xdb = (ushort*)(ws + 0);
  ushort* qb  = (ushort*)(ws + 4*MiB);
  ushort* kb  = (ushort*)(ws + 8*MiB);
  float*  x1f = (float*) (ws + 4*MiB);
  float*  sf  = (float*) (ws + 4*MiB);
  ushort* vtb = (ushort*)(ws + 12*MiB);
  float*  xdf = (float*) (ws + 12*MiB);
  ushort* hb  = (ushort*)(ws + 20*MiB);
  ushort* wqt = (ushort*)(ws + 36*MiB);
  ushort* wkt = (ushort*)(ws + 36*MiB + 128*1024);
  ushort* wvt = (ushort*)(ws + 36*MiB + 256*1024);
  ushort* wot = (ushort*)(ws + 36*MiB + 384*1024);
  ushort* w1b = (ushort*)(ws + 36*MiB + 512*1024);
  ushort* w2b = (ushort*)(ws + 36*MiB + 1024*1024);

  // 1. prep
  {
    int total = BL_*D_ + 4*D_*D_ + 2*DFF_*D_;
    prep_kernel<<<(total+255)/256, 256, 0, stream>>>(x, Wq, Wk, Wv, Wo, W1, W2,
                                                     xb, wqt, wkt, wvt, wot, w1b, w2b);
  }
  // 2. QKV projections
  qkv_gemm<<<dim3(BL_/16, 4, 3), 256, 0, stream>>>(xb, wqt, wkt, wvt, qb, kb, vtb);
  // 3. attention v2
  attn_kernel<<<dim3(L_/16, B_*H_), 256, 0, stream>>>(qb, kb, vtb, attn_out, ob);
  // 4. O projection + residual
  gemm_bt<2><<<dim3(BL_/16, D_/64), 256, 0, stream>>>(ob, wot, BL_, D_, D_, x, x1f, nullptr);
  // 5. decomp1
  decomp_kernel<0><<<BL_, 256, 0, stream>>>(x1f, xdf, xdb);
  // 6. FFN1
  gemm_bt<1><<<dim3(BL_/16, DFF_/64), 256, 0, stream>>>(xdb, w1b, BL_, DFF_, D_, nullptr, nullptr, hb);
  // 7. FFN2 + residual
  gemm_bt<2><<<dim3(BL_/16, D_/64), 256, 0, stream>>>(hb, w2b, BL_, D_, DFF_, xdf, sf, nullptr);
  // 8. decomp2 -> fp32 res
  decomp_kernel<1><<<BL_, 256, 0, stream>>>(sf, res_out, nullptr);
}

// Round 6
// 426.395 us; speedup vs baseline: 1.0854x; 1.0733x over previous
//
#include <hip/hip_runtime.h>
#include <hip/hip_bf16.h>

typedef __attribute__((ext_vector_type(8))) short bf16x8;
typedef __attribute__((ext_vector_type(4))) float f32x4;

#define B_    4
#define L_    2048
#define D_    256
#define H_    8
#define DH_   32
#define DFF_  1024
#define BL_   (B_*L_)          // 8192
#define RES_ELEMS (BL_*D_)     // 2097152

__device__ __forceinline__ float bf2f(ushort u){
  union { unsigned int i; float f; } v; v.i = ((unsigned int)u)<<16; return v.f;
}
__device__ __forceinline__ ushort f2bf(float f){
  union { float f; unsigned int i; } v; v.f = f;
  unsigned int u = v.i;
  u += 0x7fffu + ((u>>16)&1u);   // round-to-nearest-even
  return (ushort)(u>>16);
}

// ---------------- prep: fp32 -> bf16 casts + weight transposes (UNCHANGED r5) ----------------
__global__ void prep_kernel(const float* x, const float* Wq, const float* Wk, const float* Wv,
                            const float* Wo, const float* W1, const float* W2,
                            ushort* xb, ushort* wqt, ushort* wkt, ushort* wvt, ushort* wot,
                            ushort* w1b, ushort* w2b){
  int i = blockIdx.x*256 + threadIdx.x;
  const int NX = BL_*D_;
  const int NW = D_*D_;
  const int NF = DFF_*D_;
  if (i < NX) { xb[i] = f2bf(x[i]); return; }
  i -= NX;
  if (i < NW) { int c = i>>8, k = i&255; wqt[i] = f2bf(Wq[k*D_+c]); return; }
  i -= NW;
  if (i < NW) { int c = i>>8, k = i&255; wkt[i] = f2bf(Wk[k*D_+c]); return; }
  i -= NW;
  if (i < NW) { int c = i>>8, k = i&255; wvt[i] = f2bf(Wv[k*D_+c]); return; }
  i -= NW;
  if (i < NW) { int c = i>>8, k = i&255; wot[i] = f2bf(Wo[k*D_+c]); return; }
  i -= NW;
  if (i < NF) { w1b[i] = f2bf(W1[i]); return; }
  i -= NF;
  if (i < NF) { w2b[i] = f2bf(W2[i]); return; }
}

// ---------------- QKV projection GEMM (UNCHANGED r5) ----------------
__global__ __launch_bounds__(256) void qkv_gemm(const ushort* __restrict__ xb,
                         const ushort* __restrict__ wqt, const ushort* __restrict__ wkt,
                         const ushort* __restrict__ wvt,
                         ushort* __restrict__ qb, ushort* __restrict__ kb, ushort* __restrict__ vtb){
  int lane = threadIdx.x & 63, w = threadIdx.x >> 6;
  int rt = blockIdx.x, cg = blockIdx.y, mat = blockIdx.z;
  const ushort* Bt = (mat==0) ? wqt : (mat==1) ? wkt : wvt;
  int row = rt*16 + (lane & 15);
  int col = cg*64 + w*16 + (lane & 15);
  int kseg = lane >> 4;
  f32x4 acc = {0.f,0.f,0.f,0.f};
  #pragma unroll
  for (int kt = 0; kt < 8; ++kt){
    bf16x8 a = *(const bf16x8*)(xb + row*D_ + kt*32 + kseg*8);
    bf16x8 b = *(const bf16x8*)(Bt + col*D_ + kt*32 + kseg*8);
    acc = __builtin_amdgcn_mfma_f32_16x16x32_bf16(a, b, acc, 0, 0, 0);
  }
  int rbase = rt*16 + (lane>>4)*4;   // C/D: row=(lane>>4)*4+r, col=lane&15
  if (mat < 2){
    ushort* out = (mat==0) ? qb : kb;
    #pragma unroll
    for (int r = 0; r < 4; ++r) out[(size_t)(rbase+r)*D_ + col] = f2bf(acc[r]);
  } else {
    int b = rbase >> 11, l = rbase & (L_-1);
    int h = col >> 5, d = col & 31;
    ushort* p = vtb + ((size_t)((b*H_ + h)*DH_ + d))*L_ + l;
    #pragma unroll
    for (int r = 0; r < 4; ++r) p[r] = f2bf(acc[r]);
  }
}

// ---------------- attention v3: wave-private 2KB P buffer, interleaved PV ----------------
// grid (L_/16, B_*H_), block 256 (4 waves). Wave w owns k-tiles ct in [w*32, w*32+32).
// LDS: 16.9 KB total -> 8 blocks/CU (vs 2 at v2's 75 KB). Two barriers per block.
__global__ __launch_bounds__(256, 4) void attn_kernel(const ushort* __restrict__ qb,
                          const ushort* __restrict__ kb, const ushort* __restrict__ vtb,
                          float* __restrict__ attn_out, ushort* __restrict__ ob){
  __shared__ ushort Pb[4][16][64];      // wave-private P chunk (bf16), XOR-swizzled
  __shared__ float part[4*16*32];       // per-wave PV partials
  __shared__ float red[4][2][16];       // per-wave (m,s) per q-row
  int tid = threadIdx.x, lane = tid & 63, w = tid >> 6;
  int rt = blockIdx.x, bh = blockIdx.y;
  int b = bh >> 3, h = bh & 7;
  int l0 = rt*16;
  int ql = lane & 15, g = lane >> 4;    // q-row within tile, k-subgroup
  const float SCL2E = 0.17677669529663687f * 1.4426950408889634f; // 1/sqrt(32) * log2(e)

  bf16x8 qfrag = *(const bf16x8*)(qb + (size_t)(b*L_ + l0 + ql)*D_ + h*DH_ + g*8);
  const ushort* kbase = kb + (size_t)(b)*L_*D_ + h*DH_ + g*8;

  // ---- pass A: online max/sum over this wave's k-range ----
  float m = -1e30f, s = 0.f;
  for (int ct = w*32; ct < w*32 + 32; ++ct){
    bf16x8 kfrag = *(const bf16x8*)(kbase + (size_t)(ct*16 + ql)*D_);
    f32x4 acc = {0.f,0.f,0.f,0.f};
    acc = __builtin_amdgcn_mfma_f32_16x16x32_bf16(kfrag, qfrag, acc, 0, 0, 0);
    float z0 = acc[0]*SCL2E, z1 = acc[1]*SCL2E, z2 = acc[2]*SCL2E, z3 = acc[3]*SCL2E;
    float mt = fmaxf(fmaxf(z0, z1), fmaxf(z2, z3));
    float mn = fmaxf(m, mt);
    s = s*exp2f(m - mn) + (exp2f(z0 - mn) + exp2f(z1 - mn))
                        + (exp2f(z2 - mn) + exp2f(z3 - mn));
    m = mn;
  }
  // merge the 4 k-subgroups sharing a q-row
  #pragma unroll
  for (int off = 16; off <= 32; off <<= 1){
    float mo = __shfl_xor(m, off), so = __shfl_xor(s, off);
    float mn = fmaxf(m, mo);
    s = s*exp2f(m - mn) + so*exp2f(mo - mn);
    m = mn;
  }
  if (lane < 16){ red[w][0][ql] = m; red[w][1][ql] = s; }
  __syncthreads();
  {
    float M = red[0][0][ql], S = red[0][1][ql];
    #pragma unroll
    for (int w2 = 1; w2 < 4; ++w2){
      float mo = red[w2][0][ql], so = red[w2][1][ql];
      float mn = fmaxf(M, mo);
      S = S*exp2f(M - mn) + so*exp2f(mo - mn);
      M = mn;
    }
    m = M + log2f(S);   // fold 1/sum into the exp bias
  }

  // ---- pass B: per k-pair, recompute scores -> attn store + PV accumulate ----
  f32x4 acc0 = {0.f,0.f,0.f,0.f}, acc1 = {0.f,0.f,0.f,0.f};
  float* arow = attn_out + ((size_t)bh*L_ + l0 + ql)*L_;
  char* prow = (char*)&Pb[w][ql][0];
  int swz = (ql & 7) << 4;
  const ushort* v0p = vtb + ((size_t)(bh*DH_) + ql)*L_;
  const ushort* v1p = vtb + ((size_t)(bh*DH_) + 16 + ql)*L_;

  for (int j = 0; j < 16; ++j){
    #pragma unroll
    for (int par = 0; par < 2; ++par){
      int ct = w*32 + 2*j + par;
      bf16x8 kfrag = *(const bf16x8*)(kbase + (size_t)(ct*16 + ql)*D_);
      f32x4 acc = {0.f,0.f,0.f,0.f};
      acc = __builtin_amdgcn_mfma_f32_16x16x32_bf16(kfrag, qfrag, acc, 0, 0, 0);
      float p0 = exp2f(acc[0]*SCL2E - m);
      float p1 = exp2f(acc[1]*SCL2E - m);
      float p2 = exp2f(acc[2]*SCL2E - m);
      float p3 = exp2f(acc[3]*SCL2E - m);
      float4 st = {p0, p1, p2, p3};
      *(float4*)(arow + ct*16 + g*4) = st;                     // 16B coalesced attn write
      ushort4 u4 = {f2bf(p0), f2bf(p1), f2bf(p2), f2bf(p3)};
      *(ushort4*)(prow + ((par*32 + g*8) ^ swz)) = u4;         // wave-private, swizzled
    }
    // PV for this 32-k tile (k = [w*512 + j*32, +32))
    int kt = w*16 + j;
    bf16x8 pf = *(const bf16x8*)(prow + ((g*16) ^ swz));
    bf16x8 v0 = *(const bf16x8*)(v0p + kt*32 + g*8);
    bf16x8 v1 = *(const bf16x8*)(v1p + kt*32 + g*8);
    acc0 = __builtin_amdgcn_mfma_f32_16x16x32_bf16(pf, v0, acc0, 0, 0, 0);
    acc1 = __builtin_amdgcn_mfma_f32_16x16x32_bf16(pf, v1, acc1, 0, 0, 0);
  }

  {
    int rb = g*4;
    #pragma unroll
    for (int r = 0; r < 4; ++r){
      part[(w*16 + rb + r)*32 + ql]      = acc0[r];
      part[(w*16 + rb + r)*32 + 16 + ql] = acc1[r];
    }
  }
  __syncthreads();
  for (int idx = tid; idx < 512; idx += 256){
    int row = idx >> 5, d = idx & 31;
    float sum = part[(0*16+row)*32 + d] + part[(1*16+row)*32 + d]
              + part[(2*16+row)*32 + d] + part[(3*16+row)*32 + d];
    ob[(size_t)(b*L_ + l0 + row)*D_ + h*DH_ + d] = f2bf(sum);
  }
}

// ---------------- generic GEMM (UNCHANGED r5) ----------------
template<int EPI>
__global__ __launch_bounds__(256) void gemm_bt(const ushort* __restrict__ A, const ushort* __restrict__ Bt,
                        int M, int N, int K,
                        const float* __restrict__ add, float* __restrict__ outf,
                        ushort* __restrict__ outh){
  int lane = threadIdx.x & 63, w = threadIdx.x >> 6;
  int row = blockIdx.x*16 + (lane & 15);
  int col = blockIdx.y*64 + w*16 + (lane & 15);
  int kseg = lane >> 4;
  f32x4 acc = {0.f,0.f,0.f,0.f};
  const ushort* ap = A + (size_t)row*K + kseg*8;
  const ushort* bp = Bt + (size_t)col*K + kseg*8;
  int nk = K >> 5;
  for (int kt = 0; kt < nk; ++kt){
    bf16x8 a = *(const bf16x8*)(ap + kt*32);
    bf16x8 bfr = *(const bf16x8*)(bp + kt*32);
    acc = __builtin_amdgcn_mfma_f32_16x16x32_bf16(a, bfr, acc, 0, 0, 0);
  }
  int rbase = blockIdx.x*16 + (lane>>4)*4;
  #pragma unroll
  for (int r = 0; r < 4; ++r){
    size_t o = (size_t)(rbase + r)*N + col;
    float v = acc[r];
    if (EPI == 1) outh[o] = f2bf(fmaxf(v, 0.f));
    else if (EPI == 2) outf[o] = add[o] + v;
  }
}

// ---------------- circular moving-average decomp (UNCHANGED r5) ----------------
template<int WHICH>
__global__ __launch_bounds__(256) void decomp_kernel(const float* __restrict__ in,
                                                     float* __restrict__ outf,
                                                     ushort* __restrict__ outh){
  int c = threadIdx.x;
  int gl = blockIdx.x;
  int b = gl >> 11, l = gl & (L_-1);
  float s = 0.f;
  #pragma unroll
  for (int o = -3; o <= 3; ++o){
    int ll = (l + o + L_) & (L_-1);
    s += in[((size_t)(b*L_ + ll))*D_ + c];
  }
  float v = in[(size_t)gl*D_ + c] - s*(1.f/7.f);
  if (WHICH == 0){
    outf[(size_t)gl*D_ + c] = v;
    outh[(size_t)gl*D_ + c] = f2bf(v);
  } else {
    outf[(size_t)gl*D_ + c] = v;   // fp32 final res
  }
}

__global__ void ws_diag_kernel(float* res0, float encoded){
  if (threadIdx.x == 0 && blockIdx.x == 0) res0[0] = encoded;
}

extern "C" void kernel_launch(void* const* d_in, const int* in_sizes, int n_in,
                              void* d_out, int out_size, void* d_ws, size_t ws_size,
                              hipStream_t stream) {
  const float* x  = (const float*)d_in[0];
  const float* Wq = (const float*)d_in[1];
  const float* Wk = (const float*)d_in[2];
  const float* Wv = (const float*)d_in[3];
  const float* Wo = (const float*)d_in[4];
  const float* W1 = (const float*)d_in[5];
  const float* W2 = (const float*)d_in[6];

  float* out      = (float*)d_out;        // fp32 outputs
  float* res_out  = out;                  // res: 2,097,152 fp32
  float* attn_out = out + RES_ELEMS;      // attn: 134,217,728 fp32

  const size_t MiB = 1024ull*1024ull;
  const size_t NEEDED = 36*MiB + (MiB + MiB/2);   // 37.5 MiB (fits, r2-r5 verified)

  if (ws_size < NEEDED){
    float enc = 1048576.0f + 1024.0f * (float)(ws_size / MiB);
    ws_diag_kernel<<<1, 64, 0, stream>>>(res_out, enc);
    return;
  }

  char* ws = (char*)d_ws;
  ushort* xb  = (ushort*)(ws + 0);
  ushort* ob  = (ushort*)(ws + 0);
  ushort* xdb = (ushort*)(ws + 0);
  ushort* qb  = (ushort*)(ws + 4*MiB);
  ushort* kb  = (ushort*)(ws + 8*MiB);
  float*  x1f = (float*) (ws + 4*MiB);
  float*  sf  = (float*) (ws + 4*MiB);
  ushort* vtb = (ushort*)(ws + 12*MiB);
  float*  xdf = (float*) (ws + 12*MiB);
  ushort* hb  = (ushort*)(ws + 20*MiB);
  ushort* wqt = (ushort*)(ws + 36*MiB);
  ushort* wkt = (ushort*)(ws + 36*MiB + 128*1024);
  ushort* wvt = (ushort*)(ws + 36*MiB + 256*1024);
  ushort* wot = (ushort*)(ws + 36*MiB + 384*1024);
  ushort* w1b = (ushort*)(ws + 36*MiB + 512*1024);
  ushort* w2b = (ushort*)(ws + 36*MiB + 1024*1024);

  // 1. prep
  {
    int total = BL_*D_ + 4*D_*D_ + 2*DFF_*D_;
    prep_kernel<<<(total+255)/256, 256, 0, stream>>>(x, Wq, Wk, Wv, Wo, W1, W2,
                                                     xb, wqt, wkt, wvt, wot, w1b, w2b);
  }
  // 2. QKV projections
  qkv_gemm<<<dim3(BL_/16, 4, 3), 256, 0, stream>>>(xb, wqt, wkt, wvt, qb, kb, vtb);
  // 3. attention v3
  attn_kernel<<<dim3(L_/16, B_*H_), 256, 0, stream>>>(qb, kb, vtb, attn_out, ob);
  // 4. O projection + residual
  gemm_bt<2><<<dim3(BL_/16, D_/64), 256, 0, stream>>>(ob, wot, BL_, D_, D_, x, x1f, nullptr);
  // 5. decomp1
  decomp_kernel<0><<<BL_, 256, 0, stream>>>(x1f, xdf, xdb);
  // 6. FFN1
  gemm_bt<1><<<dim3(BL_/16, DFF_/64), 256, 0, stream>>>(xdb, w1b, BL_, DFF_, D_, nullptr, nullptr, hb);
  // 7. FFN2 + residual
  gemm_bt<2><<<dim3(BL_/16, D_/64), 256, 0, stream>>>(hb, w2b, BL_, D_, DFF_, xdf, sf, nullptr);
  // 8. decomp2 -> fp32 res
  decomp_kernel<1><<<BL_, 256, 0, stream>>>(sf, res_out, nullptr);
}